// Round 2
// baseline (354.681 us; speedup 1.0000x reference)
//
#include <hip/hip_runtime.h>

// PE constants:
//   w_j   = 10000^(-j/256) = exp2f(PE_C2 * j),  PE_C2 = -log2(10000)/256
//   angle = i * w_j ;  pe[i, 2j] = sin(angle), pe[i, 2j+1] = cos(angle)
// Columns 510/511 stay zero (reference uses n_pairs = 255).
// NOTE (R2 post-mortem): do NOT replace the second exp2f with a hand-derived
// ratio constant — a 5.7e-6 constant error became 0.73 absmax at i=131071.
#define PE_C2 (-0.051905126482615034f)

typedef float vfloat4 __attribute__((ext_vector_type(4)));

#define NTHR          256
#define ROWS_PER_BLK  64     // each block owns 64 contiguous rows (128 KiB out)
#define UNROLL        8      // independent gathers in flight per wave

// Block-contiguous layout, LDS-staged tokens, 8-deep gather batches.
//  - Block b owns rows [b*64, b*64+64). One coalesced 256 B load stages the
//    64 tokens into LDS; the inner loop reads tokens via LDS broadcast, so the
//    global token->gather dependency chain is eliminated.
//  - Each thread owns one float4 column slot v = tid&127; rsub = tid>>7 picks
//    even/odd rows. A wave = 64 consecutive v at one row -> 1 KiB coalesced
//    gather read and 1 KiB coalesced NT store.
//  - Inner loop issues 8 independent emb gathers back-to-back (addresses come
//    from LDS, lgkm-cheap), then consumes them in order: sincos + add + store.
//  - __launch_bounds__(256,4): cap 128 VGPRs -> >=16 waves/CU -> >=128
//    outstanding 1 KiB gathers per CU.
__global__ __launch_bounds__(NTHR, 4) void pe_gather_kernel(
    const int* __restrict__ token_ids,
    const vfloat4* __restrict__ emb,      // emb_table viewed as [VOCAB][128] float4
    vfloat4* __restrict__ out,            // [SEQ][128] float4
    int seq)                              // number of rows (131072)
{
    __shared__ int s_tok[ROWS_PER_BLK];

    const int base = blockIdx.x * ROWS_PER_BLK;
    const int v    = threadIdx.x & 127;   // float4 column slot
    const int rsub = threadIdx.x >> 7;    // 0 or 1: even/odd rows of the block

    if (threadIdx.x < ROWS_PER_BLK) {
        const int idx = base + threadIdx.x;
        s_tok[threadIdx.x] = (idx < seq) ? token_ids[idx] : 0;
    }

    // loop-invariant frequencies (keep exp2f form — see R2 note above)
    const float w0 = exp2f(PE_C2 * (float)(2 * v));
    const float w1 = exp2f(PE_C2 * (float)(2 * v + 1));
    const bool  full = (v < 127);         // v==127: second pair is j=255 -> pe 0

    __syncthreads();

    // rows covered: rsub + {0,2,...,62}; 4 outer iters x 8 unrolled rows.
    for (int kk = rsub; kk < ROWS_PER_BLK; kk += 2 * UNROLL) {
        vfloat4 e[UNROLL];
        #pragma unroll
        for (int u = 0; u < UNROLL; ++u) {
            const int tok = s_tok[kk + 2 * u];          // LDS broadcast
            e[u] = emb[(size_t)tok * 128 + v];          // independent gathers
        }
        #pragma unroll
        for (int u = 0; u < UNROLL; ++u) {
            const int row = base + kk + 2 * u;
            const float fi = (float)row;

            float s0, c0;
            __sincosf(fi * w0, &s0, &c0);

            vfloat4 r;
            r.x = e[u].x + s0;
            r.y = e[u].y + c0;

            if (full) {
                float s1, c1;
                __sincosf(fi * w1, &s1, &c1);
                r.z = e[u].z + s1;
                r.w = e[u].w + c1;
            } else {
                r.z = e[u].z;
                r.w = e[u].w;
            }

            if (row < seq)
                __builtin_nontemporal_store(r, &out[(size_t)row * 128 + v]);
        }
    }
}

extern "C" void kernel_launch(void* const* d_in, const int* in_sizes, int n_in,
                              void* d_out, int out_size, void* d_ws, size_t ws_size,
                              hipStream_t stream) {
    const int*   token_ids = (const int*)d_in[0];
    const float* emb_table = (const float*)d_in[1];

    const int seq    = in_sizes[0];                    // 131072
    const int nblk   = (seq + ROWS_PER_BLK - 1) / ROWS_PER_BLK;  // 2048

    pe_gather_kernel<<<nblk, NTHR, 0, stream>>>(
        token_ids, (const vfloat4*)emb_table, (vfloat4*)d_out, seq);
}